// Round 7
// baseline (206.246 us; speedup 1.0000x reference)
//
#include <hip/hip_runtime.h>

// Problem constants: B=1024, D=64, M=3, C=16384
#define B_   1024
#define D_   64
#define M_   3
#define C_   16384
#define NCH  8               // c-chunks per (m,br)
#define CCH  (C_ / NCH)      // 2048 c-rows per chunk (512 KB -> L2-resident)
#define CW   (CCH / 4)       // 512 c-rows per wave
#define NTL  (CW / 16)       // 32 tiles of 16 c-rows per wave

typedef __attribute__((ext_vector_type(8))) short bf16x8;   // MFMA A/B frag
typedef __attribute__((ext_vector_type(4))) float f32x4;    // MFMA acc

// truncating fp32 -> bf16 pack (validated R2-R6): low short = first arg
__device__ __forceinline__ unsigned bfpack2(float lo, float hi) {
    return __builtin_amdgcn_perm(__float_as_uint(hi), __float_as_uint(lo),
                                 0x07060302u);
}
__device__ __forceinline__ bf16x8 pack8(float4 x, float4 y) {
    union { unsigned u[4]; bf16x8 v; } r;
    r.u[0] = bfpack2(x.x, x.y);
    r.u[1] = bfpack2(x.z, x.w);
    r.u[2] = bfpack2(y.x, y.y);
    r.u[3] = bfpack2(y.z, y.w);
    return r.v;
}
__device__ __forceinline__ float fexp2(float x) {   // 2^x, one v_exp_f32
    float r; asm("v_exp_f32 %0, %1" : "=v"(r) : "v"(x)); return r;
}

// ---------------------------------------------------------------------------
// Workspace (floats): ws[0 .. 48*1024) = partial[48][B]   (~197 KB)
//   slice index = (m*2+br)*NCH + cchunk; written by plain stores (disjoint).
// d_out[0] is zeroed by lse_mfma block 0; finish atomicAdds into it.
// ---------------------------------------------------------------------------

// 768 blocks x 256 threads (4 waves), all-resident (12 waves/CU).
// Decode keeps all 16 b-blocks of one (m,br,cchunk) on one XCD: the 512 KB
// cen chunk is L2-shared (6 combos x 512 KB = 3 MB/XCD < 4 MB L2).
// Wave: A = features (64 b-rows, bf16, reg-resident); B = cen streamed with
// 2-deep register prefetch, fully unrolled (static buffer indices). D-rows
// = b fixed per lane slot -> exp2 sums accumulate in registers; no
// cross-lane ops in the loop.
__global__ __launch_bounds__(256, 3) void lse_mfma(
    const float* __restrict__ cen0, const float* __restrict__ cen1,
    const float* __restrict__ f0,   const float* __restrict__ f1,
    const float* __restrict__ conc0,const float* __restrict__ conc1,
    float* __restrict__ partial,    // [48][B_]
    float* __restrict__ out)        // d_out (zeroed here, filled by finish)
{
    if (blockIdx.x == 0 && threadIdx.x == 0) out[0] = 0.0f;

    const int bid    = blockIdx.x;
    const int xcd    = bid & 7;
    const int idx    = bid >> 3;               // 0..95
    const int combo  = xcd * 6 + (idx >> 4);   // 0..47, bijective
    const int bblk   = idx & 15;               // 0..15
    const int cchunk = combo & 7;              // 0..7
    const int mbr    = combo >> 3;             // m*2+br, 0..5
    const int br = mbr & 1, m = mbr >> 1;

    const float* __restrict__ cen  = br ? cen1  : cen0;
    const float* __restrict__ ft   = br ? f1    : f0;
    const float* __restrict__ conc = br ? conc1 : conc0;

    const int wv   = threadIdx.x >> 6;
    const int lane = threadIdx.x & 63;
    const int lrow = lane & 15;
    const int lk   = lane >> 4;                // k-group 0..3
    const int wbase = bblk * 64;               // wave's 64 b-rows
    const float LOG2E = 1.44269504088896340736f;

    // --- A fragments: 4 row-tiles of features, fp32 -> bf16, resident -----
    bf16x8 af[4][2];
#pragma unroll
    for (int t = 0; t < 4; ++t) {
        const float* fp = ft + (size_t)(wbase + t * 16 + lrow) * D_ + lk * 8;
        float4 x0 = *reinterpret_cast<const float4*>(fp);
        float4 x1 = *reinterpret_cast<const float4*>(fp + 4);
        float4 y0 = *reinterpret_cast<const float4*>(fp + 32);
        float4 y1 = *reinterpret_cast<const float4*>(fp + 36);
        af[t][0] = pack8(x0, x1);   // k = lk*8 .. +7
        af[t][1] = pack8(y0, y1);   // k = 32+lk*8 .. +7
    }

    // --- c-walk: 32 tiles of 16 rows, 2-deep register prefetch ------------
    const int cb = cchunk * CCH + wv * CW;
    const float* bp = cen  + (size_t)(m * C_ + cb + lrow) * D_ + lk * 8;
    const float* cp = conc + m * C_ + cb + lrow;

    float4 pr[2][4];
    float  pc[2];
#pragma unroll
    for (int t = 0; t < 2; ++t) {
        const float* q = bp + (size_t)t * 16 * D_;
        pr[t][0] = *reinterpret_cast<const float4*>(q);
        pr[t][1] = *reinterpret_cast<const float4*>(q + 4);
        pr[t][2] = *reinterpret_cast<const float4*>(q + 32);
        pr[t][3] = *reinterpret_cast<const float4*>(q + 36);
        pc[t]    = cp[t * 16];
    }

    float s[4][4];
#pragma unroll
    for (int t = 0; t < 4; ++t)
#pragma unroll
        for (int j = 0; j < 4; ++j) s[t][j] = 0.0f;

#pragma unroll
    for (int ct = 0; ct < NTL; ++ct) {
        const int cur = ct & 1;                 // static after full unroll
        const float4 c0 = pr[cur][0], c1 = pr[cur][1];
        const float4 c2 = pr[cur][2], c3 = pr[cur][3];
        const float  cc = pc[cur];
        if (ct + 2 < NTL) {                     // prefetch tile ct+2
            const float* q = bp + (size_t)(ct + 2) * 16 * D_;
            pr[cur][0] = *reinterpret_cast<const float4*>(q);
            pr[cur][1] = *reinterpret_cast<const float4*>(q + 4);
            pr[cur][2] = *reinterpret_cast<const float4*>(q + 32);
            pr[cur][3] = *reinterpret_cast<const float4*>(q + 36);
            pc[cur]    = cp[(ct + 2) * 16];
        }
        const bf16x8 bk0 = pack8(c0, c1);       // cen k-half 0
        const bf16x8 bk1 = pack8(c2, c3);       // cen k-half 1
        const float  ic  = LOG2E * __builtin_amdgcn_rcpf(cc);  // per-lane c

        f32x4 a0 = {0.f,0.f,0.f,0.f}, a1 = {0.f,0.f,0.f,0.f};
        f32x4 a2 = {0.f,0.f,0.f,0.f}, a3 = {0.f,0.f,0.f,0.f};
        a0 = __builtin_amdgcn_mfma_f32_16x16x32_bf16(af[0][0], bk0, a0, 0, 0, 0);
        a0 = __builtin_amdgcn_mfma_f32_16x16x32_bf16(af[0][1], bk1, a0, 0, 0, 0);
        a1 = __builtin_amdgcn_mfma_f32_16x16x32_bf16(af[1][0], bk0, a1, 0, 0, 0);
        a1 = __builtin_amdgcn_mfma_f32_16x16x32_bf16(af[1][1], bk1, a1, 0, 0, 0);
        a2 = __builtin_amdgcn_mfma_f32_16x16x32_bf16(af[2][0], bk0, a2, 0, 0, 0);
        a2 = __builtin_amdgcn_mfma_f32_16x16x32_bf16(af[2][1], bk1, a2, 0, 0, 0);
        a3 = __builtin_amdgcn_mfma_f32_16x16x32_bf16(af[3][0], bk0, a3, 0, 0, 0);
        a3 = __builtin_amdgcn_mfma_f32_16x16x32_bf16(af[3][1], bk1, a3, 0, 0, 0);

        // b-row is FIXED per (t,lk,j): accumulate exp2 in registers
#pragma unroll
        for (int j = 0; j < 4; ++j) {
            s[0][j] += fexp2(a0[j] * ic);
            s[1][j] += fexp2(a1[j] * ic);
            s[2][j] += fexp2(a2[j] * ic);
            s[3][j] += fexp2(a3[j] * ic);
        }
    }

    // --- wave tail: butterfly over 16 c-cols (lrow bits), LDS combine -----
    __shared__ float lsum[4][64];
#pragma unroll
    for (int t = 0; t < 4; ++t)
#pragma unroll
        for (int j = 0; j < 4; ++j) {
            float v = s[t][j];
            v += __shfl_xor(v, 1);
            v += __shfl_xor(v, 2);
            v += __shfl_xor(v, 4);
            v += __shfl_xor(v, 8);
            s[t][j] = v;
        }
    if (lrow == 0) {
#pragma unroll
        for (int t = 0; t < 4; ++t)
#pragma unroll
            for (int j = 0; j < 4; ++j)
                lsum[wv][t * 16 + lk * 4 + j] = s[t][j];
    }
    __syncthreads();
    if (threadIdx.x < 64) {
        const float v = lsum[0][threadIdx.x] + lsum[1][threadIdx.x]
                      + lsum[2][threadIdx.x] + lsum[3][threadIdx.x];
        // disjoint slice per block: plain store, no atomic, no pre-zero
        partial[(size_t)(mbr * NCH + cchunk) * B_ + wbase + threadIdx.x] = v;
    }
}

// Per (m,b): term = pos_logit - ln(sum of 8 partials). Wave-reduce, then
// one scaled atomicAdd per wave directly into d_out.
__global__ __launch_bounds__(256) void finish(
    const float* __restrict__ f,    const float* __restrict__ f_I,
    const float* __restrict__ cen0, const float* __restrict__ cen1,
    const float* __restrict__ conc0,const float* __restrict__ conc1,
    const int*   __restrict__ lab0, const int*   __restrict__ lab1,
    const float* __restrict__ partial, const int* __restrict__ lb,
    float* __restrict__ out)
{
    const int idx = blockIdx.x * 256 + threadIdx.x;   // 0 .. 2*M*B-1
    const int br  = idx / (M_ * B_);
    const int r   = idx - br * (M_ * B_);
    const int m   = r / B_;
    const int b   = r - m * B_;

    const float* cen  = br ? cen1  : cen0;
    const float* conc = br ? conc1 : conc0;
    const int*   lab  = br ? lab1  : lab0;
    const float* ft   = br ? f     : f_I;

    const int c = lab[r];
    const float* cr   = cen + (size_t)(m * C_ + c) * D_;
    const float* frow = ft + (size_t)b * D_;
    float a0 = 0.f, a1 = 0.f, a2 = 0.f, a3 = 0.f;
#pragma unroll
    for (int d = 0; d < D_; d += 4) {
        a0 = fmaf(cr[d + 0], frow[d + 0], a0);
        a1 = fmaf(cr[d + 1], frow[d + 1], a1);
        a2 = fmaf(cr[d + 2], frow[d + 2], a2);
        a3 = fmaf(cr[d + 3], frow[d + 3], a3);
    }
    const float logit = ((a0 + a1) + (a2 + a3)) / conc[(size_t)m * C_ + c];

    float ls = 0.0f;
    const float* pp = partial + (size_t)((m * 2 + br) * NCH) * B_ + b;
#pragma unroll
    for (int k = 0; k < NCH; ++k) ls += pp[k * B_];

    float term = logit - __logf(ls);

#pragma unroll
    for (int off = 32; off > 0; off >>= 1)
        term += __shfl_down(term, off);
    if ((threadIdx.x & 63) == 0) {
        const float scale = -0.5f * (float)lb[0] / (float)(B_ * M_);
        atomicAdd(out, scale * term);
    }
}

extern "C" void kernel_launch(void* const* d_in, const int* in_sizes, int n_in,
                              void* d_out, int out_size, void* d_ws, size_t ws_size,
                              hipStream_t stream) {
    const float* f      = (const float*)d_in[0];
    const float* f_I    = (const float*)d_in[1];
    const float* cen    = (const float*)d_in[2];
    const float* cen_I  = (const float*)d_in[3];
    const float* conc   = (const float*)d_in[4];
    const float* conc_I = (const float*)d_in[5];
    const int*   lab    = (const int*)d_in[6];
    const int*   lab_I  = (const int*)d_in[7];
    const int*   lb     = (const int*)d_in[8];

    float* partial = (float*)d_ws;         // 48 * 1024 floats (~197 KB)
    float* out     = (float*)d_out;

    // branch 0: cen x features_I ; branch 1: cen_I x features
    lse_mfma<<<768, 256, 0, stream>>>(cen, cen_I, f_I, f, conc, conc_I,
                                      partial, out);

    finish<<<(2 * M_ * B_) / 256, 256, 0, stream>>>(
        f, f_I, cen, cen_I, conc, conc_I, lab, lab_I, partial, lb, out);
}

// Round 8
// 125.437 us; speedup vs baseline: 1.6442x; 1.6442x over previous
//
#include <hip/hip_runtime.h>

// Problem constants: B=1024, D=64, M=3, C=16384
#define B_   1024
#define D_   64
#define M_   3
#define C_   16384
#define NCH  32              // c-chunks per (m,br)
#define CCH  (C_ / NCH)      // 512 c-rows per chunk (128 KB, L2-local)
#define NTL  (CCH / 16)      // 32 tiles of 16 c-rows per block

typedef __attribute__((ext_vector_type(8))) short bf16x8;   // MFMA A/B frag
typedef __attribute__((ext_vector_type(4))) float f32x4;    // MFMA acc

// truncating fp32 -> bf16 pack (validated R2-R7): low short = first arg
__device__ __forceinline__ unsigned bfpack2(float lo, float hi) {
    return __builtin_amdgcn_perm(__float_as_uint(hi), __float_as_uint(lo),
                                 0x07060302u);
}
__device__ __forceinline__ bf16x8 pack8(float4 x, float4 y) {
    union { unsigned u[4]; bf16x8 v; } r;
    r.u[0] = bfpack2(x.x, x.y);
    r.u[1] = bfpack2(x.z, x.w);
    r.u[2] = bfpack2(y.x, y.y);
    r.u[3] = bfpack2(y.z, y.w);
    return r.v;
}
__device__ __forceinline__ float fexp2(float x) {   // 2^x, one v_exp_f32
    float r; asm("v_exp_f32 %0, %1" : "=v"(r) : "v"(x)); return r;
}
// async global->LDS, 16 B per lane; lds base must be wave-uniform
__device__ __forceinline__ void gll16(const void* g, void* l) {
    __builtin_amdgcn_global_load_lds(
        (const __attribute__((address_space(1))) void*)g,
        (__attribute__((address_space(3))) void*)l, 16, 0, 0);
}

// ---------------------------------------------------------------------------
// Workspace (floats):
//   ws[0 .. 6144)      wsum[2][M][B]  (zeroed by hipMemsetAsync)
//   ws[6144 .. )       fbf: fragment-major bf16 features [2][64][2][64][8]
//                      (2*8192 frags * 16 B = 256 KB)   total ~287 KB
// ---------------------------------------------------------------------------

// Pack features into MFMA-A fragment order so lse's A-loads are contiguous:
// frag (br, bt, h, lane) holds f[bt*16 + (lane&15)][h*32 + (lane>>4)*8 .. +7]
__global__ __launch_bounds__(256) void prep(
    const float* __restrict__ f, const float* __restrict__ f_I,
    unsigned short* __restrict__ fbf)
{
    const int t    = blockIdx.x * 256 + threadIdx.x;  // 0..16383
    const int br   = t >> 13;
    const int r    = t & 8191;
    const int bt   = r >> 7;
    const int h    = (r >> 6) & 1;
    const int lane = r & 63;
    const int b    = bt * 16 + (lane & 15);
    const int d0   = h * 32 + (lane >> 4) * 8;
    const float* src = (br ? f : f_I) + (size_t)b * D_ + d0;  // br0 = f_I
    const float4 x = *reinterpret_cast<const float4*>(src);
    const float4 y = *reinterpret_cast<const float4*>(src + 4);
    *reinterpret_cast<bf16x8*>(fbf + (size_t)t * 8) = pack8(x, y);
}

// 768 blocks x 256 threads (4 waves), 3 waves/SIMD all-resident.
// Decode: xcd = bid&7; 24 (mbr,cchunk) combos per XCD (chunk L2-local,
// 24*128KB = 3MB/XCD); 4 b-blocks share each chunk via L2.
// Block: 4 waves own 4x64 distinct b; ALL consume the same cen tile from
// LDS (double-buffered, staged by ONE coalesced global_load_lds per tile,
// XOR-swizzled source so swizzled ds_read_b128 is conflict-free).
// exp2 sums accumulate in registers (D-row = b fixed per lane slot).
__global__ __launch_bounds__(256, 3) void lse_mfma(
    const float* __restrict__ cen0, const float* __restrict__ cen1,
    const unsigned short* __restrict__ fbf,
    const float* __restrict__ conc0, const float* __restrict__ conc1,
    float* __restrict__ wsum)       // [2][M][B]
{
    __shared__ float tbuf[2][1024];   // 2 x 4 KB cen tile buffers
    __shared__ float cbuf[CCH];       // conc chunk, 2 KB
    __shared__ float lsum[4][64];

    const int bid    = blockIdx.x;
    const int xcd    = bid & 7;
    const int i2     = bid >> 3;            // 0..95
    const int pp     = i2 >> 2;             // 0..23
    const int bblk   = i2 & 3;              // 0..3
    const int combo  = xcd * 24 + pp;       // 0..191 bijective
    const int cchunk = combo & 31;          // 0..31
    const int mbr    = combo >> 5;          // 0..5
    const int br = mbr & 1, m = mbr >> 1;

    const float* __restrict__ cen  = br ? cen1  : cen0;
    const float* __restrict__ conc = br ? conc1 : conc0;

    const int tid  = threadIdx.x;
    const int wv   = tid >> 6;
    const int lane = tid & 63;
    const int lrow = lane & 15;
    const int lk   = lane >> 4;
    const int wbase = bblk * 256 + wv * 64;     // wave's 64 b-rows
    const float LOG2E = 1.44269504088896340736f;

    // --- A fragments: contiguous loads from fragment-major fbf ------------
    const unsigned short* fbb = fbf + (size_t)br * 8192 * 8;
    bf16x8 af[4][2];
#pragma unroll
    for (int t = 0; t < 4; ++t)
#pragma unroll
        for (int h = 0; h < 2; ++h)
            af[t][h] = *reinterpret_cast<const bf16x8*>(
                fbb + ((size_t)(((wbase >> 4) + t) * 2 + h) * 64 + lane) * 8);

    // --- staging source (inverse-swizzled so LDS reads are swizzled) ------
    const int cb = cchunk * CCH;
    const int srow = tid >> 4;                       // 0..15
    const int soff = ((tid & 15) << 4) ^ ((srow & 7) << 4);
    const char* csrc = (const char*)(cen + ((size_t)m * C_ + cb) * D_)
                     + srow * 256 + soff;

    // prologue: stage tile 0 + conc chunk, then drain
    gll16(csrc, (char*)tbuf[0] + wv * 1024);
    if (tid < 128)
        gll16((const char*)(conc + (size_t)m * C_ + cb) + tid * 16,
              (char*)cbuf + wv * 1024);
    __syncthreads();

    float s[4][4];
#pragma unroll
    for (int t = 0; t < 4; ++t)
#pragma unroll
        for (int j = 0; j < 4; ++j) s[t][j] = 0.0f;

    const unsigned swz = (unsigned)((lrow & 7) << 4);
    int cur = 0;
    for (int ct = 0; ct < NTL; ++ct) {
        // stage tile ct+1 into the other buffer (async, drained by barrier)
        if (ct + 1 < NTL)
            gll16(csrc + (size_t)(ct + 1) * 4096,
                  (char*)tbuf[cur ^ 1] + wv * 1024);

        // swizzled b128 reads of this tile (each lane: row lrow, d lk*8..)
        const char* bp = (const char*)tbuf[cur] + lrow * 256;
        const float4 r00 = *(const float4*)(bp + ((lk * 32      ) ^ swz));
        const float4 r01 = *(const float4*)(bp + ((lk * 32 + 16 ) ^ swz));
        const float4 r10 = *(const float4*)(bp + ((128 + lk * 32     ) ^ swz));
        const float4 r11 = *(const float4*)(bp + ((128 + lk * 32 + 16) ^ swz));
        const float  cc  = cbuf[ct * 16 + lrow];

        const bf16x8 bk0 = pack8(r00, r01);    // k = 0..31 slot
        const bf16x8 bk1 = pack8(r10, r11);    // k = 32..63 slot
        const float  ic  = LOG2E * __builtin_amdgcn_rcpf(cc);

        f32x4 a0 = {0.f,0.f,0.f,0.f}, a1 = {0.f,0.f,0.f,0.f};
        f32x4 a2 = {0.f,0.f,0.f,0.f}, a3 = {0.f,0.f,0.f,0.f};
        a0 = __builtin_amdgcn_mfma_f32_16x16x32_bf16(af[0][0], bk0, a0, 0, 0, 0);
        a0 = __builtin_amdgcn_mfma_f32_16x16x32_bf16(af[0][1], bk1, a0, 0, 0, 0);
        a1 = __builtin_amdgcn_mfma_f32_16x16x32_bf16(af[1][0], bk0, a1, 0, 0, 0);
        a1 = __builtin_amdgcn_mfma_f32_16x16x32_bf16(af[1][1], bk1, a1, 0, 0, 0);
        a2 = __builtin_amdgcn_mfma_f32_16x16x32_bf16(af[2][0], bk0, a2, 0, 0, 0);
        a2 = __builtin_amdgcn_mfma_f32_16x16x32_bf16(af[2][1], bk1, a2, 0, 0, 0);
        a3 = __builtin_amdgcn_mfma_f32_16x16x32_bf16(af[3][0], bk0, a3, 0, 0, 0);
        a3 = __builtin_amdgcn_mfma_f32_16x16x32_bf16(af[3][1], bk1, a3, 0, 0, 0);

        // b-row fixed per (t,lk,j): accumulate exp2 in registers
#pragma unroll
        for (int j = 0; j < 4; ++j) {
            s[0][j] += fexp2(a0[j] * ic);
            s[1][j] += fexp2(a1[j] * ic);
            s[2][j] += fexp2(a2[j] * ic);
            s[3][j] += fexp2(a3[j] * ic);
        }

        __syncthreads();    // implies vmcnt(0): next tile staged + reads done
        cur ^= 1;
    }

    // --- epilogue: butterfly over 16 c-cols (lrow bits), then atomics -----
#pragma unroll
    for (int t = 0; t < 4; ++t)
#pragma unroll
        for (int j = 0; j < 4; ++j) {
            float v = s[t][j];
            v += __shfl_xor(v, 1);
            v += __shfl_xor(v, 2);
            v += __shfl_xor(v, 4);
            v += __shfl_xor(v, 8);
            s[t][j] = v;
        }
    if (lrow == 0) {
#pragma unroll
        for (int t = 0; t < 4; ++t)
#pragma unroll
            for (int j = 0; j < 4; ++j)
                lsum[wv][t * 16 + lk * 4 + j] = s[t][j];
    }
    __syncthreads();
    atomicAdd(&wsum[(size_t)(br * M_ + m) * B_ + bblk * 256 + tid],
              lsum[tid >> 6][tid & 63]);
}

// Per (m,b): term = pos_logit - ln(wsum). Wave-reduce, one scaled atomic
// per wave directly into d_out (pre-zeroed by memset).
__global__ __launch_bounds__(256) void finish(
    const float* __restrict__ f,    const float* __restrict__ f_I,
    const float* __restrict__ cen0, const float* __restrict__ cen1,
    const float* __restrict__ conc0,const float* __restrict__ conc1,
    const int*   __restrict__ lab0, const int*   __restrict__ lab1,
    const float* __restrict__ wsum, const int* __restrict__ lb,
    float* __restrict__ out)
{
    const int idx = blockIdx.x * 256 + threadIdx.x;   // 0 .. 2*M*B-1
    const int br  = idx / (M_ * B_);
    const int r   = idx - br * (M_ * B_);
    const int m   = r / B_;
    const int b   = r - m * B_;

    const float* cen  = br ? cen1  : cen0;
    const float* conc = br ? conc1 : conc0;
    const int*   lab  = br ? lab1  : lab0;
    const float* ft   = br ? f     : f_I;

    const int c = lab[r];
    const float* cr   = cen + (size_t)(m * C_ + c) * D_;
    const float* frow = ft + (size_t)b * D_;
    float a0 = 0.f, a1 = 0.f, a2 = 0.f, a3 = 0.f;
#pragma unroll
    for (int d = 0; d < D_; d += 4) {
        a0 = fmaf(cr[d + 0], frow[d + 0], a0);
        a1 = fmaf(cr[d + 1], frow[d + 1], a1);
        a2 = fmaf(cr[d + 2], frow[d + 2], a2);
        a3 = fmaf(cr[d + 3], frow[d + 3], a3);
    }
    const float logit = ((a0 + a1) + (a2 + a3)) / conc[(size_t)m * C_ + c];
    float term = logit - __logf(wsum[idx]);

#pragma unroll
    for (int off = 32; off > 0; off >>= 1)
        term += __shfl_down(term, off);
    if ((threadIdx.x & 63) == 0) {
        const float scale = -0.5f * (float)lb[0] / (float)(B_ * M_);
        atomicAdd(out, scale * term);
    }
}

extern "C" void kernel_launch(void* const* d_in, const int* in_sizes, int n_in,
                              void* d_out, int out_size, void* d_ws, size_t ws_size,
                              hipStream_t stream) {
    const float* f      = (const float*)d_in[0];
    const float* f_I    = (const float*)d_in[1];
    const float* cen    = (const float*)d_in[2];
    const float* cen_I  = (const float*)d_in[3];
    const float* conc   = (const float*)d_in[4];
    const float* conc_I = (const float*)d_in[5];
    const int*   lab    = (const int*)d_in[6];
    const int*   lab_I  = (const int*)d_in[7];
    const int*   lb     = (const int*)d_in[8];

    float* ws   = (float*)d_ws;
    float* wsum = ws;                                   // 6144 floats
    unsigned short* fbf = (unsigned short*)(ws + 6144); // 256 KB
    float* out  = (float*)d_out;

    hipMemsetAsync(wsum, 0, 6144 * sizeof(float), stream);
    hipMemsetAsync(out, 0, sizeof(float), stream);

    prep<<<64, 256, 0, stream>>>(f, f_I, fbf);

    // branch 0: cen x features_I ; branch 1: cen_I x features
    lse_mfma<<<768, 256, 0, stream>>>(cen, cen_I, fbf, conc, conc_I, wsum);

    finish<<<(2 * M_ * B_) / 256, 256, 0, stream>>>(
        f, f_I, cen, cen_I, conc, conc_I, lab, lab_I, wsum, lb, out);
}

// Round 10
// 118.304 us; speedup vs baseline: 1.7434x; 1.0603x over previous
//
#include <hip/hip_runtime.h>

// Problem constants: B=1024, D=64, M=3, C=16384
#define B_   1024
#define D_   64
#define M_   3
#define C_   16384
#define NCH  32              // c-chunks per (m,br)
#define CCH  (C_ / NCH)      // 512 c-rows per chunk (128 KB, L2-local)
#define TROWS 64             // c-rows per staged tile (16 KB)
#define NTL  (CCH / TROWS)   // 8 tiles per block -> 8 barriers

typedef __attribute__((ext_vector_type(8))) short bf16x8;   // MFMA A/B frag
typedef __attribute__((ext_vector_type(4))) float f32x4;    // MFMA acc

// truncating fp32 -> bf16 pack (validated R2-R8): low short = first arg
__device__ __forceinline__ unsigned bfpack2(float lo, float hi) {
    return __builtin_amdgcn_perm(__float_as_uint(hi), __float_as_uint(lo),
                                 0x07060302u);
}
__device__ __forceinline__ bf16x8 pack8(float4 x, float4 y) {
    union { unsigned u[4]; bf16x8 v; } r;
    r.u[0] = bfpack2(x.x, x.y);
    r.u[1] = bfpack2(x.z, x.w);
    r.u[2] = bfpack2(y.x, y.y);
    r.u[3] = bfpack2(y.z, y.w);
    return r.v;
}
__device__ __forceinline__ float fexp2(float x) {   // 2^x, one v_exp_f32
    float r; asm("v_exp_f32 %0, %1" : "=v"(r) : "v"(x)); return r;
}
// async global->LDS, 16 B per lane; lds base must be wave-uniform
__device__ __forceinline__ void gll16(const void* g, void* l) {
    __builtin_amdgcn_global_load_lds(
        (const __attribute__((address_space(1))) void*)g,
        (__attribute__((address_space(3))) void*)l, 16, 0, 0);
}

// ---------------------------------------------------------------------------
// Workspace (floats):
//   ws[0 .. 6144)      wsum[2][M][B]   (zeroed by prep)
//   ws[6144 .. )       fbf: fragment-major bf16 features [2][64][2][64][8]
// ---------------------------------------------------------------------------

// Pack features into MFMA-A fragment order AND zero wsum / d_out.
__global__ __launch_bounds__(256) void prep(
    const float* __restrict__ f, const float* __restrict__ f_I,
    unsigned short* __restrict__ fbf, float* __restrict__ wsum,
    float* __restrict__ out)
{
    const int t    = blockIdx.x * 256 + threadIdx.x;  // 0..16383
    const int br   = t >> 13;
    const int r    = t & 8191;
    const int bt   = r >> 7;
    const int h    = (r >> 6) & 1;
    const int lane = r & 63;
    const int b    = bt * 16 + (lane & 15);
    const int d0   = h * 32 + (lane >> 4) * 8;
    const float* src = (br ? f : f_I) + (size_t)b * D_ + d0;  // br0 = f_I
    const float4 x = *reinterpret_cast<const float4*>(src);
    const float4 y = *reinterpret_cast<const float4*>(src + 4);
    *reinterpret_cast<bf16x8*>(fbf + (size_t)t * 8) = pack8(x, y);
    if (t < 2 * M_ * B_) wsum[t] = 0.0f;
    if (t == 16383) out[0] = 0.0f;
}

// 768 blocks x 256 threads (4 waves), 3 blocks/CU all-resident.
// Decode: xcd = bid&7; 24 (mbr,cchunk) combos per XCD (128 KB chunk
// L2-local, 24*128KB = 3MB/XCD); 4 b-blocks share each chunk via L2.
// Per tile (64 c-rows, 16 KB): ONE cooperative staging pass (4 coalesced
// global_load_lds per thread, XOR-swizzled source), 4 compute sub-tiles
// (4 swizzled ds_read_b128 + 8 MFMA + 16 exp2 each), ONE barrier.
// exp2 sums accumulate in registers (D-row = b fixed per lane slot).
__global__ __launch_bounds__(256, 3) void lse_mfma(
    const float* __restrict__ cen0, const float* __restrict__ cen1,
    const unsigned short* __restrict__ fbf,
    const float* __restrict__ conc0, const float* __restrict__ conc1,
    float* __restrict__ wsum)       // [2][M][B]
{
    __shared__ float tbuf[2][4096];   // 2 x 16 KB cen tile buffers
    __shared__ float lsum[4][64];

    const int bid    = blockIdx.x;
    const int xcd    = bid & 7;
    const int i2     = bid >> 3;            // 0..95
    const int pp     = i2 >> 2;             // 0..23
    const int bblk   = i2 & 3;              // 0..3
    const int combo  = xcd * 24 + pp;       // 0..191 bijective
    const int cchunk = combo & 31;          // 0..31
    const int mbr    = combo >> 5;          // 0..5
    const int br = mbr & 1, m = mbr >> 1;

    const float* __restrict__ cen  = br ? cen1  : cen0;
    const float* __restrict__ conc = br ? conc1 : conc0;

    const int tid  = threadIdx.x;
    const int wv   = tid >> 6;
    const int lane = tid & 63;
    const int lrow = lane & 15;
    const int lk   = lane >> 4;
    const int wbase = bblk * 256 + wv * 64;     // wave's 64 b-rows
    const float LOG2E = 1.44269504088896340736f;

    // --- A fragments: contiguous loads from fragment-major fbf ------------
    const unsigned short* fbb = fbf + (size_t)br * 8192 * 8;
    bf16x8 af[4][2];
#pragma unroll
    for (int t = 0; t < 4; ++t)
#pragma unroll
        for (int h = 0; h < 2; ++h)
            af[t][h] = *reinterpret_cast<const bf16x8*>(
                fbb + ((size_t)(((wbase >> 4) + t) * 2 + h) * 64 + lane) * 8);

    // --- staging geometry: tile = 64 rows x 256 B; thread covers 4 segs ---
    const int cb = cchunk * CCH;
    const char* cbase = (const char*)(cen + ((size_t)m * C_ + cb) * D_);
    int soff[4];
#pragma unroll
    for (int s2 = 0; s2 < 4; ++s2) {
        const int row = s2 * 16 + (tid >> 4);              // 0..63
        soff[s2] = row * 256 + ((((tid & 15) << 4)) ^ ((row & 7) << 4));
    }
    const int dseg = wv * 1024;   // gll16 dest: wave-uniform + lane*16

    // prologue: stage tile 0
#pragma unroll
    for (int s2 = 0; s2 < 4; ++s2)
        gll16(cbase + soff[s2], (char*)tbuf[0] + s2 * 4096 + dseg);
    __syncthreads();

    float s[4][4];
#pragma unroll
    for (int t = 0; t < 4; ++t)
#pragma unroll
        for (int j = 0; j < 4; ++j) s[t][j] = 0.0f;

    const unsigned swz = (unsigned)((lrow & 7) << 4);
    const float* ccp = conc + (size_t)m * C_ + cb + lrow;
    int cur = 0;
    for (int ct = 0; ct < NTL; ++ct) {
        if (ct + 1 < NTL) {                  // stage next tile (async)
#pragma unroll
            for (int s2 = 0; s2 < 4; ++s2)
                gll16(cbase + (size_t)(ct + 1) * 16384 + soff[s2],
                      (char*)tbuf[cur ^ 1] + s2 * 4096 + dseg);
        }
#pragma unroll
        for (int st = 0; st < 4; ++st) {     // 4 compute sub-tiles
            const char* bp = (const char*)tbuf[cur] + st * 4096 + lrow * 256;
            const float4 r00 = *(const float4*)(bp + ((lk * 32      ) ^ swz));
            const float4 r01 = *(const float4*)(bp + ((lk * 32 + 16 ) ^ swz));
            const float4 r10 = *(const float4*)(bp + ((128 + lk * 32     ) ^ swz));
            const float4 r11 = *(const float4*)(bp + ((128 + lk * 32 + 16) ^ swz));
            const float  cc  = ccp[ct * 64 + st * 16];

            const bf16x8 bk0 = pack8(r00, r01);    // k = 0..31 slot
            const bf16x8 bk1 = pack8(r10, r11);    // k = 32..63 slot
            const float  ic  = LOG2E * __builtin_amdgcn_rcpf(cc);

            f32x4 a0 = {0.f,0.f,0.f,0.f}, a1 = {0.f,0.f,0.f,0.f};
            f32x4 a2 = {0.f,0.f,0.f,0.f}, a3 = {0.f,0.f,0.f,0.f};
            a0 = __builtin_amdgcn_mfma_f32_16x16x32_bf16(af[0][0], bk0, a0, 0, 0, 0);
            a0 = __builtin_amdgcn_mfma_f32_16x16x32_bf16(af[0][1], bk1, a0, 0, 0, 0);
            a1 = __builtin_amdgcn_mfma_f32_16x16x32_bf16(af[1][0], bk0, a1, 0, 0, 0);
            a1 = __builtin_amdgcn_mfma_f32_16x16x32_bf16(af[1][1], bk1, a1, 0, 0, 0);
            a2 = __builtin_amdgcn_mfma_f32_16x16x32_bf16(af[2][0], bk0, a2, 0, 0, 0);
            a2 = __builtin_amdgcn_mfma_f32_16x16x32_bf16(af[2][1], bk1, a2, 0, 0, 0);
            a3 = __builtin_amdgcn_mfma_f32_16x16x32_bf16(af[3][0], bk0, a3, 0, 0, 0);
            a3 = __builtin_amdgcn_mfma_f32_16x16x32_bf16(af[3][1], bk1, a3, 0, 0, 0);

            // b-row fixed per (t,lk,j): accumulate exp2 in registers
#pragma unroll
            for (int j = 0; j < 4; ++j) {
                s[0][j] += fexp2(a0[j] * ic);
                s[1][j] += fexp2(a1[j] * ic);
                s[2][j] += fexp2(a2[j] * ic);
                s[3][j] += fexp2(a3[j] * ic);
            }
        }
        __syncthreads();   // tile ct reads done; tile ct+1 staged (vmcnt 0)
        cur ^= 1;
    }

    // --- epilogue: butterfly over 16 c-cols (lrow bits), then atomics -----
#pragma unroll
    for (int t = 0; t < 4; ++t)
#pragma unroll
        for (int j = 0; j < 4; ++j) {
            float v = s[t][j];
            v += __shfl_xor(v, 1);
            v += __shfl_xor(v, 2);
            v += __shfl_xor(v, 4);
            v += __shfl_xor(v, 8);
            s[t][j] = v;
        }
    if (lrow == 0) {
#pragma unroll
        for (int t = 0; t < 4; ++t)
#pragma unroll
            for (int j = 0; j < 4; ++j)
                lsum[wv][t * 16 + lk * 4 + j] = s[t][j];
    }
    __syncthreads();
    atomicAdd(&wsum[(size_t)(br * M_ + m) * B_ + bblk * 256 + tid],
              lsum[tid >> 6][tid & 63]);
}

// Per (m,b): term = pos_logit - ln(wsum). Wave-reduce, one scaled atomic
// per wave directly into d_out (zeroed by prep).
__global__ __launch_bounds__(256) void finish(
    const float* __restrict__ f,    const float* __restrict__ f_I,
    const float* __restrict__ cen0, const float* __restrict__ cen1,
    const float* __restrict__ conc0,const float* __restrict__ conc1,
    const int*   __restrict__ lab0, const int*   __restrict__ lab1,
    const float* __restrict__ wsum, const int* __restrict__ lb,
    float* __restrict__ out)
{
    const int idx = blockIdx.x * 256 + threadIdx.x;   // 0 .. 2*M*B-1
    const int br  = idx / (M_ * B_);
    const int r   = idx - br * (M_ * B_);
    const int m   = r / B_;
    const int b   = r - m * B_;

    const float* cen  = br ? cen1  : cen0;
    const float* conc = br ? conc1 : conc0;
    const int*   lab  = br ? lab1  : lab0;
    const float* ft   = br ? f     : f_I;

    const int c = lab[r];
    const float* cr   = cen + (size_t)(m * C_ + c) * D_;
    const float* frow = ft + (size_t)b * D_;
    float a0 = 0.f, a1 = 0.f, a2 = 0.f, a3 = 0.f;
#pragma unroll
    for (int d = 0; d < D_; d += 4) {
        a0 = fmaf(cr[d + 0], frow[d + 0], a0);
        a1 = fmaf(cr[d + 1], frow[d + 1], a1);
        a2 = fmaf(cr[d + 2], frow[d + 2], a2);
        a3 = fmaf(cr[d + 3], frow[d + 3], a3);
    }
    const float logit = ((a0 + a1) + (a2 + a3)) / conc[(size_t)m * C_ + c];
    float term = logit - __logf(wsum[idx]);

#pragma unroll
    for (int off = 32; off > 0; off >>= 1)
        term += __shfl_down(term, off);
    if ((threadIdx.x & 63) == 0) {
        const float scale = -0.5f * (float)lb[0] / (float)(B_ * M_);
        atomicAdd(out, scale * term);
    }
}

extern "C" void kernel_launch(void* const* d_in, const int* in_sizes, int n_in,
                              void* d_out, int out_size, void* d_ws, size_t ws_size,
                              hipStream_t stream) {
    const float* f      = (const float*)d_in[0];
    const float* f_I    = (const float*)d_in[1];
    const float* cen    = (const float*)d_in[2];
    const float* cen_I  = (const float*)d_in[3];
    const float* conc   = (const float*)d_in[4];
    const float* conc_I = (const float*)d_in[5];
    const int*   lab    = (const int*)d_in[6];
    const int*   lab_I  = (const int*)d_in[7];
    const int*   lb     = (const int*)d_in[8];

    float* ws   = (float*)d_ws;
    float* wsum = ws;                                   // 6144 floats
    unsigned short* fbf = (unsigned short*)(ws + 6144); // 256 KB
    float* out  = (float*)d_out;

    prep<<<64, 256, 0, stream>>>(f, f_I, fbf, wsum, out);

    // branch 0: cen x features_I ; branch 1: cen_I x features
    lse_mfma<<<768, 256, 0, stream>>>(cen, cen_I, fbf, conc, conc_I, wsum);

    finish<<<(2 * M_ * B_) / 256, 256, 0, stream>>>(
        f, f_I, cen, cen_I, conc, conc_I, lab, lab_I, wsum, lb, out);
}